// Round 5
// baseline (301.309 us; speedup 1.0000x reference)
//
#include <hip/hip_runtime.h>
#include <float.h>

#define BATCH 4

typedef float f32x2 __attribute__((ext_vector_type(2)));

// Pack points as (-2x, -2y, -2z, |q|^2) for both sets; init out to +FLT_MAX.
__global__ void chamfer_prep(const float* __restrict__ xyz1,
                             const float* __restrict__ xyz2,
                             float4* __restrict__ pk1,
                             float4* __restrict__ pk2,
                             float* __restrict__ out,
                             int n1, int n2, int out_n) {
    int i = blockIdx.x * blockDim.x + threadIdx.x;
    if (i < n1) {
        float x = xyz1[3 * (size_t)i], y = xyz1[3 * (size_t)i + 1], z = xyz1[3 * (size_t)i + 2];
        pk1[i] = make_float4(-2.f * x, -2.f * y, -2.f * z, fmaf(x, x, fmaf(y, y, z * z)));
    }
    if (i < n2) {
        float x = xyz2[3 * (size_t)i], y = xyz2[3 * (size_t)i + 1], z = xyz2[3 * (size_t)i + 2];
        pk2[i] = make_float4(-2.f * x, -2.f * y, -2.f * z, fmaf(x, x, fmaf(y, y, z * z)));
    }
    if (i < out_n) out[i] = FLT_MAX;
}

// Fused both-direction kernel, packed-fp32 inner loop.
// LDS chunk is transposed into dst-point PAIRS:
//   s[2t]   = (x0, x1, y0, y1)
//   s[2t+1] = (z0, z1, w0, w1)
// Per pair of dst points and per src point:
//   e01 = pk_fma(x01, px, pk_fma(y01, py, pk_fma(z01, pz, w01)))
//   m   = min3(m, e0, e1)
// min_j |p-q|^2 = psq + min_j( qsq - 2 p.q ); psq applied in epilogue.
// CHUNK=128 -> 2048 blocks -> 8 blocks/CU, 32 waves/CU (needs VGPR<=64,
// enforced by __launch_bounds__(TPB, 8)) so LDS latency hides across waves.
template<int TPB, int CHUNK, int P>
__global__ __launch_bounds__(TPB, 8) void chamfer_fused(
        const float* __restrict__ xyz1,   // (B, N, 3) raw
        const float* __restrict__ xyz2,   // (B, M, 3) raw
        const float4* __restrict__ pk1,   // (B, N) packed
        const float4* __restrict__ pk2,   // (B, M) packed
        float* __restrict__ out,          // (B*N) ++ (B*M)
        int N, int M, int blocks_dir0) {
    __shared__ float4 s[CHUNK];

    int bid = blockIdx.x;
    const int dir = (bid >= blocks_dir0) ? 1 : 0;
    if (dir) bid -= blocks_dir0;

    const int Nsrc = dir ? M : N;
    const int Mdst = dir ? N : M;
    const float* src   = dir ? xyz2 : xyz1;
    const float4* dstp = dir ? pk1  : pk2;
    float* outd        = dir ? (out + (size_t)BATCH * N) : out;

    const int YT = Nsrc / (TPB * P);   // src tiles
    const int Z  = Mdst / CHUNK;       // dst chunks
    const int b  = bid / (YT * Z);
    const int r  = bid % (YT * Z);
    const int yt = r / Z;
    const int z  = r % Z;

    // Stage + transpose the dst chunk into pair-packed layout.
    const float4* dchunk = dstp + (size_t)b * Mdst + (size_t)z * CHUNK;
    for (int t = threadIdx.x; t < CHUNK / 2; t += TPB) {
        const float4 q0 = dchunk[2 * t];
        const float4 q1 = dchunk[2 * t + 1];
        s[2 * t]     = make_float4(q0.x, q1.x, q0.y, q1.y);
        s[2 * t + 1] = make_float4(q0.z, q1.z, q0.w, q1.w);
    }

    // P src points per thread, components duplicated for packed math
    // (compiler keeps one copy via VOP3P op_sel).
    const int i0 = yt * (TPB * P) + threadIdx.x;
    f32x2 px[P], py[P], pz[P];
    float psq[P], m[P];
    #pragma unroll
    for (int k = 0; k < P; ++k) {
        const int i = i0 + k * TPB;
        const float* p = src + ((size_t)b * Nsrc + i) * 3;
        const float x = p[0], y = p[1], zc = p[2];
        px[k] = (f32x2){x, x};
        py[k] = (f32x2){y, y};
        pz[k] = (f32x2){zc, zc};
        psq[k] = fmaf(x, x, fmaf(y, y, zc * zc));
        m[k] = FLT_MAX;
    }
    __syncthreads();

    #pragma unroll 8
    for (int jj = 0; jj < CHUNK / 2; ++jj) {
        const float4 A = s[2 * jj];       // (x0,x1,y0,y1) broadcast
        const float4 B = s[2 * jj + 1];   // (z0,z1,w0,w1) broadcast
        const f32x2 xq = (f32x2){A.x, A.y};
        const f32x2 yq = (f32x2){A.z, A.w};
        const f32x2 zq = (f32x2){B.x, B.y};
        const f32x2 wq = (f32x2){B.z, B.w};
        #pragma unroll
        for (int k = 0; k < P; ++k) {
            const f32x2 e = __builtin_elementwise_fma(xq, px[k],
                             __builtin_elementwise_fma(yq, py[k],
                              __builtin_elementwise_fma(zq, pz[k], wq)));
            m[k] = fminf(fminf(m[k], e.x), e.y);   // -> v_min3_f32
        }
    }

    #pragma unroll
    for (int k = 0; k < P; ++k) {
        const int i = i0 + k * TPB;
        const float d = fmaxf(psq[k] + m[k], 0.0f);  // >=0 keeps int-min ordering
        atomicMin((int*)&outd[(size_t)b * Nsrc + i], __float_as_int(d));
    }
}

// ---- Fallback path (ws too small / odd sizes): proven round-1 LDS kernel ----
__global__ void chamfer_init_out(float* __restrict__ out, int n) {
    int i = blockIdx.x * blockDim.x + threadIdx.x;
    if (i < n) out[i] = FLT_MAX;
}

template<int TPB, int CHUNK>
__global__ __launch_bounds__(TPB) void chamfer_min_lds(
        const float* __restrict__ src, const float* __restrict__ dst,
        float* __restrict__ out, int N, int M) {
    __shared__ float s[CHUNK * 3];
    const int b  = blockIdx.x;
    const int i  = blockIdx.y * TPB + threadIdx.x;
    const int j0 = blockIdx.z * CHUNK;
    const float* p = src + ((size_t)b * N + i) * 3;
    const float px = p[0], py = p[1], pz = p[2];
    const float* dchunk = dst + ((size_t)b * M + j0) * 3;
    constexpr int NVEC = CHUNK * 3 / 4;
    for (int t = threadIdx.x; t < NVEC; t += TPB)
        ((float4*)s)[t] = ((const float4*)dchunk)[t];
    __syncthreads();
    float best = FLT_MAX;
    #pragma unroll 8
    for (int j = 0; j < CHUNK; ++j) {
        const float dx = px - s[3 * j + 0];
        const float dy = py - s[3 * j + 1];
        const float dz = pz - s[3 * j + 2];
        float d = dx * dx;
        d = fmaf(dy, dy, d);
        d = fmaf(dz, dz, d);
        best = fminf(best, d);
    }
    atomicMin((int*)&out[(size_t)b * N + i], __float_as_int(best));
}

extern "C" void kernel_launch(void* const* d_in, const int* in_sizes, int n_in,
                              void* d_out, int out_size, void* d_ws, size_t ws_size,
                              hipStream_t stream) {
    const float* xyz1 = (const float*)d_in[0];
    const float* xyz2 = (const float*)d_in[1];
    float* out = (float*)d_out;

    const int N = in_sizes[0] / (BATCH * 3);  // 8192
    const int M = in_sizes[1] / (BATCH * 3);  // 8192
    const int n1 = BATCH * N, n2 = BATCH * M;

    constexpr int TPB = 256;
    constexpr int CHUNK = 128;   // 2 KiB LDS; Z=64 -> 2048 blocks = 8/CU
    constexpr int P = 8;

    const size_t need = ((size_t)n1 + (size_t)n2) * sizeof(float4);
    const bool divisible = (N % (TPB * P) == 0) && (M % (TPB * P) == 0) &&
                           (N % CHUNK == 0) && (M % CHUNK == 0);

    if (ws_size >= need && divisible) {
        float4* pk1 = (float4*)d_ws;
        float4* pk2 = pk1 + n1;
        int prep_n = out_size > n1 ? out_size : n1;
        if (n2 > prep_n) prep_n = n2;
        chamfer_prep<<<(prep_n + TPB - 1) / TPB, TPB, 0, stream>>>(
            xyz1, xyz2, pk1, pk2, out, n1, n2, out_size);

        const int blocks_dir0 = BATCH * (N / (TPB * P)) * (M / CHUNK);
        const int blocks_dir1 = BATCH * (M / (TPB * P)) * (N / CHUNK);
        chamfer_fused<TPB, CHUNK, P><<<blocks_dir0 + blocks_dir1, TPB, 0, stream>>>(
            xyz1, xyz2, pk1, pk2, out, N, M, blocks_dir0);
    } else {
        constexpr int LCHUNK = 1024;
        chamfer_init_out<<<(out_size + TPB - 1) / TPB, TPB, 0, stream>>>(out, out_size);
        dim3 g1(BATCH, N / TPB, M / LCHUNK);
        chamfer_min_lds<TPB, LCHUNK><<<g1, TPB, 0, stream>>>(xyz1, xyz2, out, N, M);
        dim3 g2(BATCH, M / TPB, N / LCHUNK);
        chamfer_min_lds<TPB, LCHUNK><<<g2, TPB, 0, stream>>>(xyz2, xyz1, out + n1, M, N);
    }
}

// Round 6
// 49.396 us; speedup vs baseline: 6.0999x; 6.0999x over previous
//
#include <hip/hip_runtime.h>
#include <float.h>

#define BATCH 4

typedef float f32x2 __attribute__((ext_vector_type(2)));

// Pack points as (-2x, -2y, -2z, |q|^2) for both sets; init out to +FLT_MAX.
__global__ void chamfer_prep(const float* __restrict__ xyz1,
                             const float* __restrict__ xyz2,
                             float4* __restrict__ pk1,
                             float4* __restrict__ pk2,
                             float* __restrict__ out,
                             int n1, int n2, int out_n) {
    int i = blockIdx.x * blockDim.x + threadIdx.x;
    if (i < n1) {
        float x = xyz1[3 * (size_t)i], y = xyz1[3 * (size_t)i + 1], z = xyz1[3 * (size_t)i + 2];
        pk1[i] = make_float4(-2.f * x, -2.f * y, -2.f * z, fmaf(x, x, fmaf(y, y, z * z)));
    }
    if (i < n2) {
        float x = xyz2[3 * (size_t)i], y = xyz2[3 * (size_t)i + 1], z = xyz2[3 * (size_t)i + 2];
        pk2[i] = make_float4(-2.f * x, -2.f * y, -2.f * z, fmaf(x, x, fmaf(y, y, z * z)));
    }
    if (i < out_n) out[i] = FLT_MAX;
}

// Fused both-direction kernel, packed-fp32 inner loop.
// LDS chunk is transposed into dst-point PAIRS:
//   s[2t]   = (x0, x1, y0, y1)
//   s[2t+1] = (z0, z1, w0, w1)
// Per pair of dst points and per src point:
//   e01 = pk_fma(x01, px, pk_fma(y01, py, pk_fma(z01, pz, w01)))
//   m   = min3(m, e0, e1)
// min_j |p-q|^2 = psq + min_j( qsq - 2 p.q ); psq applied in epilogue.
//
// NOTE: no min-waves __launch_bounds__ — R5 showed forcing 8 waves/EU
// squeezed VGPR 52->32 and spilled the inner loop to scratch (568MB fetch).
// 52 VGPR <= 64 already permits 8 waves/SIMD; occupancy comes from the
// 2048-block grid (CHUNK=128 -> 8 blocks/CU).
template<int TPB, int CHUNK, int P>
__global__ __launch_bounds__(TPB) void chamfer_fused(
        const float* __restrict__ xyz1,   // (B, N, 3) raw
        const float* __restrict__ xyz2,   // (B, M, 3) raw
        const float4* __restrict__ pk1,   // (B, N) packed
        const float4* __restrict__ pk2,   // (B, M) packed
        float* __restrict__ out,          // (B*N) ++ (B*M)
        int N, int M, int blocks_dir0) {
    __shared__ float4 s[CHUNK];

    int bid = blockIdx.x;
    const int dir = (bid >= blocks_dir0) ? 1 : 0;
    if (dir) bid -= blocks_dir0;

    const int Nsrc = dir ? M : N;
    const int Mdst = dir ? N : M;
    const float* src   = dir ? xyz2 : xyz1;
    const float4* dstp = dir ? pk1  : pk2;
    float* outd        = dir ? (out + (size_t)BATCH * N) : out;

    const int YT = Nsrc / (TPB * P);   // src tiles
    const int Z  = Mdst / CHUNK;       // dst chunks
    const int b  = bid / (YT * Z);
    const int r  = bid % (YT * Z);
    const int yt = r / Z;
    const int z  = r % Z;

    // Stage + transpose the dst chunk into pair-packed layout.
    const float4* dchunk = dstp + (size_t)b * Mdst + (size_t)z * CHUNK;
    for (int t = threadIdx.x; t < CHUNK / 2; t += TPB) {
        const float4 q0 = dchunk[2 * t];
        const float4 q1 = dchunk[2 * t + 1];
        s[2 * t]     = make_float4(q0.x, q1.x, q0.y, q1.y);
        s[2 * t + 1] = make_float4(q0.z, q1.z, q0.w, q1.w);
    }

    // P src points per thread, components duplicated for packed math.
    const int i0 = yt * (TPB * P) + threadIdx.x;
    f32x2 px[P], py[P], pz[P];
    float psq[P], m[P];
    #pragma unroll
    for (int k = 0; k < P; ++k) {
        const int i = i0 + k * TPB;
        const float* p = src + ((size_t)b * Nsrc + i) * 3;
        const float x = p[0], y = p[1], zc = p[2];
        px[k] = (f32x2){x, x};
        py[k] = (f32x2){y, y};
        pz[k] = (f32x2){zc, zc};
        psq[k] = fmaf(x, x, fmaf(y, y, zc * zc));
        m[k] = FLT_MAX;
    }
    __syncthreads();

    #pragma unroll 8
    for (int jj = 0; jj < CHUNK / 2; ++jj) {
        const float4 A = s[2 * jj];       // (x0,x1,y0,y1) broadcast
        const float4 B = s[2 * jj + 1];   // (z0,z1,w0,w1) broadcast
        const f32x2 xq = (f32x2){A.x, A.y};
        const f32x2 yq = (f32x2){A.z, A.w};
        const f32x2 zq = (f32x2){B.x, B.y};
        const f32x2 wq = (f32x2){B.z, B.w};
        #pragma unroll
        for (int k = 0; k < P; ++k) {
            const f32x2 e = __builtin_elementwise_fma(xq, px[k],
                             __builtin_elementwise_fma(yq, py[k],
                              __builtin_elementwise_fma(zq, pz[k], wq)));
            m[k] = fminf(fminf(m[k], e.x), e.y);   // -> v_min3_f32
        }
    }

    #pragma unroll
    for (int k = 0; k < P; ++k) {
        const int i = i0 + k * TPB;
        const float d = fmaxf(psq[k] + m[k], 0.0f);  // >=0 keeps int-min ordering
        atomicMin((int*)&outd[(size_t)b * Nsrc + i], __float_as_int(d));
    }
}

// ---- Fallback path (ws too small / odd sizes): proven round-1 LDS kernel ----
__global__ void chamfer_init_out(float* __restrict__ out, int n) {
    int i = blockIdx.x * blockDim.x + threadIdx.x;
    if (i < n) out[i] = FLT_MAX;
}

template<int TPB, int CHUNK>
__global__ __launch_bounds__(TPB) void chamfer_min_lds(
        const float* __restrict__ src, const float* __restrict__ dst,
        float* __restrict__ out, int N, int M) {
    __shared__ float s[CHUNK * 3];
    const int b  = blockIdx.x;
    const int i  = blockIdx.y * TPB + threadIdx.x;
    const int j0 = blockIdx.z * CHUNK;
    const float* p = src + ((size_t)b * N + i) * 3;
    const float px = p[0], py = p[1], pz = p[2];
    const float* dchunk = dst + ((size_t)b * M + j0) * 3;
    constexpr int NVEC = CHUNK * 3 / 4;
    for (int t = threadIdx.x; t < NVEC; t += TPB)
        ((float4*)s)[t] = ((const float4*)dchunk)[t];
    __syncthreads();
    float best = FLT_MAX;
    #pragma unroll 8
    for (int j = 0; j < CHUNK; ++j) {
        const float dx = px - s[3 * j + 0];
        const float dy = py - s[3 * j + 1];
        const float dz = pz - s[3 * j + 2];
        float d = dx * dx;
        d = fmaf(dy, dy, d);
        d = fmaf(dz, dz, d);
        best = fminf(best, d);
    }
    atomicMin((int*)&out[(size_t)b * N + i], __float_as_int(best));
}

extern "C" void kernel_launch(void* const* d_in, const int* in_sizes, int n_in,
                              void* d_out, int out_size, void* d_ws, size_t ws_size,
                              hipStream_t stream) {
    const float* xyz1 = (const float*)d_in[0];
    const float* xyz2 = (const float*)d_in[1];
    float* out = (float*)d_out;

    const int N = in_sizes[0] / (BATCH * 3);  // 8192
    const int M = in_sizes[1] / (BATCH * 3);  // 8192
    const int n1 = BATCH * N, n2 = BATCH * M;

    constexpr int TPB = 256;
    constexpr int CHUNK = 128;   // 2 KiB LDS; Z=64 -> 2048 blocks = 8/CU
    constexpr int P = 8;

    const size_t need = ((size_t)n1 + (size_t)n2) * sizeof(float4);
    const bool divisible = (N % (TPB * P) == 0) && (M % (TPB * P) == 0) &&
                           (N % CHUNK == 0) && (M % CHUNK == 0);

    if (ws_size >= need && divisible) {
        float4* pk1 = (float4*)d_ws;
        float4* pk2 = pk1 + n1;
        int prep_n = out_size > n1 ? out_size : n1;
        if (n2 > prep_n) prep_n = n2;
        chamfer_prep<<<(prep_n + TPB - 1) / TPB, TPB, 0, stream>>>(
            xyz1, xyz2, pk1, pk2, out, n1, n2, out_size);

        const int blocks_dir0 = BATCH * (N / (TPB * P)) * (M / CHUNK);
        const int blocks_dir1 = BATCH * (M / (TPB * P)) * (N / CHUNK);
        chamfer_fused<TPB, CHUNK, P><<<blocks_dir0 + blocks_dir1, TPB, 0, stream>>>(
            xyz1, xyz2, pk1, pk2, out, N, M, blocks_dir0);
    } else {
        constexpr int LCHUNK = 1024;
        chamfer_init_out<<<(out_size + TPB - 1) / TPB, TPB, 0, stream>>>(out, out_size);
        dim3 g1(BATCH, N / TPB, M / LCHUNK);
        chamfer_min_lds<TPB, LCHUNK><<<g1, TPB, 0, stream>>>(xyz1, xyz2, out, N, M);
        dim3 g2(BATCH, M / TPB, N / LCHUNK);
        chamfer_min_lds<TPB, LCHUNK><<<g2, TPB, 0, stream>>>(xyz2, xyz1, out + n1, M, N);
    }
}

// Round 7
// 41.769 us; speedup vs baseline: 7.2136x; 1.1826x over previous
//
#include <hip/hip_runtime.h>
#include <float.h>

#define BATCH 4

typedef _Float16 half4 __attribute__((ext_vector_type(4)));
typedef float f32x4 __attribute__((ext_vector_type(4)));
typedef float f32x2 __attribute__((ext_vector_type(2)));

// ================= MFMA path =================
// D[i,j] = |p_i|^2 + |q_j|^2 - 2 p.q  via K=13 fp16 slots (exact split trick):
//  A[p] = [hx,hy,hz, hx,hy,hz, ex,ey,ez, ps_h, ps_e, 1, 1, 0,0,0]
//  B[q] = [-2hx,-2hy,-2hz, -2ex,-2ey,-2ez, -2hx,-2hy,-2hz, 1, 1, qs_h, qs_e, 0,0,0]
// fp16*fp16 products are exact in the fp32 accumulator; only the dropped
// e.e term (~1e-6) and fp16(e) residual remain.

__device__ inline void pack_point(float x, float y, float z,
                                  _Float16* __restrict__ A, _Float16* __restrict__ B) {
    const _Float16 hx = (_Float16)x, hy = (_Float16)y, hz = (_Float16)z;
    const _Float16 ex = (_Float16)(x - (float)hx);
    const _Float16 ey = (_Float16)(y - (float)hy);
    const _Float16 ez = (_Float16)(z - (float)hz);
    const float ps = fmaf(x, x, fmaf(y, y, z * z));
    const _Float16 ph = (_Float16)ps;
    const _Float16 pe = (_Float16)(ps - (float)ph);
    const _Float16 one = (_Float16)1.0f, zero = (_Float16)0.0f;

    A[0]=hx; A[1]=hy; A[2]=hz; A[3]=hx; A[4]=hy; A[5]=hz;
    A[6]=ex; A[7]=ey; A[8]=ez; A[9]=ph; A[10]=pe; A[11]=one; A[12]=one;
    A[13]=zero; A[14]=zero; A[15]=zero;

    B[0]=(_Float16)(-2.0f*(float)hx); B[1]=(_Float16)(-2.0f*(float)hy); B[2]=(_Float16)(-2.0f*(float)hz);
    B[3]=(_Float16)(-2.0f*(float)ex); B[4]=(_Float16)(-2.0f*(float)ey); B[5]=(_Float16)(-2.0f*(float)ez);
    B[6]=B[0]; B[7]=B[1]; B[8]=B[2];
    B[9]=one; B[10]=one; B[11]=ph; B[12]=pe;
    B[13]=zero; B[14]=zero; B[15]=zero;
}

__global__ void prep_fp16(const float* __restrict__ x1, const float* __restrict__ x2,
                          _Float16* __restrict__ pa1, _Float16* __restrict__ pb1,
                          _Float16* __restrict__ pa2, _Float16* __restrict__ pb2,
                          float* __restrict__ out, int n1, int n2, int outn) {
    const int i = blockIdx.x * blockDim.x + threadIdx.x;
    if (i < n1) {
        const float* p = x1 + 3 * (size_t)i;
        pack_point(p[0], p[1], p[2], pa1 + 16 * (size_t)i, pb1 + 16 * (size_t)i);
    }
    if (i < n2) {
        const float* p = x2 + 3 * (size_t)i;
        pack_point(p[0], p[1], p[2], pa2 + 16 * (size_t)i, pb2 + 16 * (size_t)i);
    }
    if (i < outn) out[i] = FLT_MAX;
}

// Block: 4 waves, each wave owns IT=4 i-tiles (64 rows) -> 256 rows/block.
// Sweeps a j-segment of N/NJ cols in LDS stages of 256 cols (16 j-tiles).
// LDS layout is fragment-order, j-tile-paired: byte addr of lane l, tile t:
//   (t/2)*1024 + l*16 + (t&1)*8   -> one ds_read_b128 yields 2 B-frags.
template<int NJ>
__global__ __launch_bounds__(256) void chamfer_mfma(
        const _Float16* __restrict__ pa1, const _Float16* __restrict__ pb1,
        const _Float16* __restrict__ pa2, const _Float16* __restrict__ pb2,
        float* __restrict__ out, int N) {
    constexpr int IT = 4;
    __shared__ unsigned long long sB[1024];   // 8 KiB

    const int tid  = threadIdx.x;
    const int lane = tid & 63;
    const int w    = tid >> 6;

    int bid = blockIdx.x;
    const int RB      = N / 256;
    const int per_dir = BATCH * RB * NJ;
    const int dir = bid / per_dir;  bid %= per_dir;
    const int b   = bid / (RB * NJ); bid %= (RB * NJ);
    const int rb  = bid / NJ;
    const int js  = bid % NJ;

    const _Float16* pa = dir ? pa2 : pa1;
    const _Float16* pb = dir ? pb1 : pb2;
    float* outd = out + (size_t)dir * BATCH * N + (size_t)b * N;

    // A fragments: row = lane&15, k-group = lane>>4 (8B each), from global.
    const int rowbase = rb * 256 + w * 64;
    const unsigned long long* ga = (const unsigned long long*)pa;
    half4 af[IT];
    #pragma unroll
    for (int it = 0; it < IT; ++it) {
        const int row = rowbase + it * 16 + (lane & 15);
        af[it] = __builtin_bit_cast(half4, ga[(size_t)(b * N + row) * 4 + (lane >> 4)]);
    }

    f32x4 rmin[IT];
    #pragma unroll
    for (int it = 0; it < IT; ++it)
        rmin[it] = (f32x4){FLT_MAX, FLT_MAX, FLT_MAX, FLT_MAX};
    const f32x4 cz = (f32x4){0.f, 0.f, 0.f, 0.f};

    const int jseg   = N / NJ;
    const int stages = jseg / 256;
    const unsigned long long* gb = (const unsigned long long*)pb;

    for (int s = 0; s < stages; ++s) {
        const int jb = js * jseg + s * 256;
        // ---- stage 256 cols into LDS (issue loads before the barrier) ----
        const size_t q = (size_t)(b * N + jb + tid) * 4;
        const unsigned long long v0 = gb[q], v1 = gb[q+1], v2 = gb[q+2], v3 = gb[q+3];
        const int tpart = tid >> 4, j = tid & 15;
        const int base  = ((tpart >> 1) << 7) + (j << 1) + (tpart & 1);
        __syncthreads();                    // prior stage fully consumed
        sB[base] = v0; sB[base + 32] = v1; sB[base + 64] = v2; sB[base + 96] = v3;
        __syncthreads();

        // ---- 16 j-tiles as 8 pairs ----
        #pragma unroll
        for (int p = 0; p < 8; ++p) {
            const half4 b0 = __builtin_bit_cast(half4, sB[p * 128 + lane * 2]);
            const half4 b1 = __builtin_bit_cast(half4, sB[p * 128 + lane * 2 + 1]);
            #pragma unroll
            for (int it = 0; it < IT; ++it) {
                const f32x4 d = __builtin_amdgcn_mfma_f32_16x16x16f16(af[it], b0, cz, 0, 0, 0);
                rmin[it] = __builtin_elementwise_min(rmin[it], d);
            }
            #pragma unroll
            for (int it = 0; it < IT; ++it) {
                const f32x4 d = __builtin_amdgcn_mfma_f32_16x16x16f16(af[it], b1, cz, 0, 0, 0);
                rmin[it] = __builtin_elementwise_min(rmin[it], d);
            }
        }
    }

    // ---- reduce over the 16 col-lanes, then atomicMin per row ----
    #pragma unroll
    for (int it = 0; it < IT; ++it) {
        #pragma unroll
        for (int e = 0; e < 4; ++e) {
            float v = rmin[it][e];
            v = fminf(v, __shfl_xor(v, 1, 64));
            v = fminf(v, __shfl_xor(v, 2, 64));
            v = fminf(v, __shfl_xor(v, 4, 64));
            v = fminf(v, __shfl_xor(v, 8, 64));
            rmin[it][e] = v;
        }
        if ((lane & 15) == 0) {
            const int r0 = rowbase + it * 16 + (lane >> 4) * 4;
            #pragma unroll
            for (int e = 0; e < 4; ++e) {
                const float v = fmaxf(rmin[it][e], 0.0f);  // >=0 keeps int-min ordering
                atomicMin((int*)&outd[r0 + e], __float_as_int(v));
            }
        }
    }
}

// ================= fallback: R6 pk-fma path =================
__global__ void chamfer_prep(const float* __restrict__ xyz1,
                             const float* __restrict__ xyz2,
                             float4* __restrict__ pk1,
                             float4* __restrict__ pk2,
                             float* __restrict__ out,
                             int n1, int n2, int out_n) {
    int i = blockIdx.x * blockDim.x + threadIdx.x;
    if (i < n1) {
        float x = xyz1[3 * (size_t)i], y = xyz1[3 * (size_t)i + 1], z = xyz1[3 * (size_t)i + 2];
        pk1[i] = make_float4(-2.f * x, -2.f * y, -2.f * z, fmaf(x, x, fmaf(y, y, z * z)));
    }
    if (i < n2) {
        float x = xyz2[3 * (size_t)i], y = xyz2[3 * (size_t)i + 1], z = xyz2[3 * (size_t)i + 2];
        pk2[i] = make_float4(-2.f * x, -2.f * y, -2.f * z, fmaf(x, x, fmaf(y, y, z * z)));
    }
    if (i < out_n) out[i] = FLT_MAX;
}

template<int TPB, int CHUNK, int P>
__global__ __launch_bounds__(TPB) void chamfer_fused(
        const float* __restrict__ xyz1, const float* __restrict__ xyz2,
        const float4* __restrict__ pk1, const float4* __restrict__ pk2,
        float* __restrict__ out, int N, int M, int blocks_dir0) {
    __shared__ float4 s[CHUNK];
    int bid = blockIdx.x;
    const int dir = (bid >= blocks_dir0) ? 1 : 0;
    if (dir) bid -= blocks_dir0;
    const int Nsrc = dir ? M : N;
    const int Mdst = dir ? N : M;
    const float* src   = dir ? xyz2 : xyz1;
    const float4* dstp = dir ? pk1  : pk2;
    float* outd        = dir ? (out + (size_t)BATCH * N) : out;
    const int YT = Nsrc / (TPB * P);
    const int Z  = Mdst / CHUNK;
    const int b  = bid / (YT * Z);
    const int r  = bid % (YT * Z);
    const int yt = r / Z;
    const int z  = r % Z;
    const float4* dchunk = dstp + (size_t)b * Mdst + (size_t)z * CHUNK;
    for (int t = threadIdx.x; t < CHUNK / 2; t += TPB) {
        const float4 q0 = dchunk[2 * t];
        const float4 q1 = dchunk[2 * t + 1];
        s[2 * t]     = make_float4(q0.x, q1.x, q0.y, q1.y);
        s[2 * t + 1] = make_float4(q0.z, q1.z, q0.w, q1.w);
    }
    const int i0 = yt * (TPB * P) + threadIdx.x;
    f32x2 px[P], py[P], pz[P];
    float psq[P], m[P];
    #pragma unroll
    for (int k = 0; k < P; ++k) {
        const int i = i0 + k * TPB;
        const float* p = src + ((size_t)b * Nsrc + i) * 3;
        const float x = p[0], y = p[1], zc = p[2];
        px[k] = (f32x2){x, x}; py[k] = (f32x2){y, y}; pz[k] = (f32x2){zc, zc};
        psq[k] = fmaf(x, x, fmaf(y, y, zc * zc));
        m[k] = FLT_MAX;
    }
    __syncthreads();
    #pragma unroll 8
    for (int jj = 0; jj < CHUNK / 2; ++jj) {
        const float4 A = s[2 * jj];
        const float4 B = s[2 * jj + 1];
        const f32x2 xq = (f32x2){A.x, A.y};
        const f32x2 yq = (f32x2){A.z, A.w};
        const f32x2 zq = (f32x2){B.x, B.y};
        const f32x2 wq = (f32x2){B.z, B.w};
        #pragma unroll
        for (int k = 0; k < P; ++k) {
            const f32x2 e = __builtin_elementwise_fma(xq, px[k],
                             __builtin_elementwise_fma(yq, py[k],
                              __builtin_elementwise_fma(zq, pz[k], wq)));
            m[k] = fminf(fminf(m[k], e.x), e.y);
        }
    }
    #pragma unroll
    for (int k = 0; k < P; ++k) {
        const int i = i0 + k * TPB;
        const float d = fmaxf(psq[k] + m[k], 0.0f);
        atomicMin((int*)&outd[(size_t)b * Nsrc + i], __float_as_int(d));
    }
}

extern "C" void kernel_launch(void* const* d_in, const int* in_sizes, int n_in,
                              void* d_out, int out_size, void* d_ws, size_t ws_size,
                              hipStream_t stream) {
    const float* xyz1 = (const float*)d_in[0];
    const float* xyz2 = (const float*)d_in[1];
    float* out = (float*)d_out;

    const int N = in_sizes[0] / (BATCH * 3);  // 8192
    const int M = in_sizes[1] / (BATCH * 3);  // 8192
    const int n1 = BATCH * N, n2 = BATCH * M;

    constexpr int TPB = 256;
    constexpr int NJ = 8;

    const size_t need16 = ((size_t)n1 + (size_t)n2) * 64;  // A+B fp16 forms
    const bool mfma_ok = (N == M) && (N % 2048 == 0) && (ws_size >= need16);

    if (mfma_ok) {
        _Float16* pa1 = (_Float16*)d_ws;
        _Float16* pb1 = pa1 + (size_t)n1 * 16;
        _Float16* pa2 = pb1 + (size_t)n1 * 16;
        _Float16* pb2 = pa2 + (size_t)n2 * 16;
        int prep_n = out_size > n1 ? out_size : n1;
        if (n2 > prep_n) prep_n = n2;
        prep_fp16<<<(prep_n + TPB - 1) / TPB, TPB, 0, stream>>>(
            xyz1, xyz2, pa1, pb1, pa2, pb2, out, n1, n2, out_size);

        const int grid = 2 * BATCH * (N / 256) * NJ;   // 2048
        chamfer_mfma<NJ><<<grid, TPB, 0, stream>>>(pa1, pb1, pa2, pb2, out, N);
        return;
    }

    // fallback: R6 pk-fma path
    constexpr int CHUNK = 128;
    constexpr int P = 8;
    const size_t need = ((size_t)n1 + (size_t)n2) * sizeof(float4);
    if (ws_size >= need && (N % (TPB * P) == 0) && (M % (TPB * P) == 0) &&
        (N % CHUNK == 0) && (M % CHUNK == 0)) {
        float4* pk1 = (float4*)d_ws;
        float4* pk2 = pk1 + n1;
        int prep_n = out_size > n1 ? out_size : n1;
        if (n2 > prep_n) prep_n = n2;
        chamfer_prep<<<(prep_n + TPB - 1) / TPB, TPB, 0, stream>>>(
            xyz1, xyz2, pk1, pk2, out, n1, n2, out_size);
        const int blocks_dir0 = BATCH * (N / (TPB * P)) * (M / CHUNK);
        const int blocks_dir1 = BATCH * (M / (TPB * P)) * (N / CHUNK);
        chamfer_fused<TPB, CHUNK, P><<<blocks_dir0 + blocks_dir1, TPB, 0, stream>>>(
            xyz1, xyz2, pk1, pk2, out, N, M, blocks_dir0);
    }
}